// Round 1
// baseline (728.152 us; speedup 1.0000x reference)
//
#include <hip/hip_runtime.h>

namespace {

constexpr int Sn = 256;   // encoder sequence length
constexpr int Dn = 8;     // input feature dim
constexpr int Tn = 12;    // decoder length

__device__ __forceinline__ float rcp_(float x) { return __builtin_amdgcn_rcpf(x); }
// sigmoid(x) = 1/(1+e^-x); saturates cleanly: e^inf -> inf -> rcp -> 0
__device__ __forceinline__ float sigm_(float x) { return rcp_(1.0f + __expf(-x)); }
// tanh(x) = 1 - 2/(e^{2x}+1); x->+inf: 1-0=1, x->-inf: 1-2=-1 (no inf/inf NaN)
__device__ __forceinline__ float tanh_(float x) { return 1.0f - 2.0f * rcp_(__expf(2.0f * x) + 1.0f); }

// gate order from jnp.split: i=[0:4), f=[4:8), g=[8:12), o=[12:16)
__device__ __forceinline__ void cell_update(const float* g, float* h, float* c) {
#pragma unroll
  for (int u = 0; u < 4; ++u) {
    float iv = sigm_(g[u]);
    float fv = sigm_(g[4 + u]);
    float gv = tanh_(g[8 + u]);
    float ov = sigm_(g[12 + u]);
    float cn = fmaf(fv, c[u], iv * gv);
    c[u] = cn;
    h[u] = ov * tanh_(cn);
  }
}

// LDS weight layout (floats):
//   [0..128)   enc_Wih0 (16x8)
//   [128..192) enc_Whh0 (16x4)
//   [192..208) enc_b0 (bih+bhh combined)
//   [208..272) enc_Wih1 (16x4)
//   [272..336) enc_Whh1 (16x4)
//   [336..352) enc_b1
//   [352..368) dec_Wih0 (16x1)
//   [368..432) dec_Whh0 (16x4)
//   [432..448) dec_b0
//   [448..512) dec_Wih1 (16x4)
//   [512..576) dec_Whh1 (16x4)
//   [576..592) dec_b1
//   [592..596) fc_W (4)
//   [596]      fc_b

__global__ __launch_bounds__(64) void seq2seq_kernel(
    const float* __restrict__ src, const float* __restrict__ trg,
    const float* __restrict__ eWih0, const float* __restrict__ eWhh0,
    const float* __restrict__ ebih0, const float* __restrict__ ebhh0,
    const float* __restrict__ eWih1, const float* __restrict__ eWhh1,
    const float* __restrict__ ebih1, const float* __restrict__ ebhh1,
    const float* __restrict__ dWih0, const float* __restrict__ dWhh0,
    const float* __restrict__ dbih0, const float* __restrict__ dbhh0,
    const float* __restrict__ dWih1, const float* __restrict__ dWhh1,
    const float* __restrict__ dbih1, const float* __restrict__ dbhh1,
    const float* __restrict__ fcW, const float* __restrict__ fcb,
    float* __restrict__ out) {
  __shared__ float w[600];
  const int tid = threadIdx.x;
  const int bs = blockDim.x;
  for (int i = tid; i < 128; i += bs) w[i] = eWih0[i];
  for (int i = tid; i < 64; i += bs) w[128 + i] = eWhh0[i];
  for (int i = tid; i < 16; i += bs) w[192 + i] = ebih0[i] + ebhh0[i];
  for (int i = tid; i < 64; i += bs) w[208 + i] = eWih1[i];
  for (int i = tid; i < 64; i += bs) w[272 + i] = eWhh1[i];
  for (int i = tid; i < 16; i += bs) w[336 + i] = ebih1[i] + ebhh1[i];
  for (int i = tid; i < 16; i += bs) w[352 + i] = dWih0[i];
  for (int i = tid; i < 64; i += bs) w[368 + i] = dWhh0[i];
  for (int i = tid; i < 16; i += bs) w[432 + i] = dbih0[i] + dbhh0[i];
  for (int i = tid; i < 64; i += bs) w[448 + i] = dWih1[i];
  for (int i = tid; i < 64; i += bs) w[512 + i] = dWhh1[i];
  for (int i = tid; i < 16; i += bs) w[576 + i] = dbih1[i] + dbhh1[i];
  if (tid < 4) w[592 + tid] = fcW[tid];
  if (tid == 0) w[596] = fcb[0];
  __syncthreads();

  const int b = blockIdx.x * bs + tid;
  const float4* sp = (const float4*)(src + (size_t)b * (Sn * Dn));

  float h0[4] = {0, 0, 0, 0}, c0[4] = {0, 0, 0, 0};
  float h1[4] = {0, 0, 0, 0}, c1[4] = {0, 0, 0, 0};

  const float* W0i = w;
  const float* W0h = w + 128;
  const float* b0 = w + 192;
  const float* W1i = w + 208;
  const float* W1h = w + 272;
  const float* b1 = w + 336;

  // ---------------- encoder: 256 steps ----------------
  for (int t = 0; t < Sn; ++t) {
    float4 xa = sp[2 * t];
    float4 xb = sp[2 * t + 1];
    float x[8] = {xa.x, xa.y, xa.z, xa.w, xb.x, xb.y, xb.z, xb.w};
    float g[16];
#pragma unroll
    for (int r = 0; r < 16; ++r) {
      float acc = b0[r];
#pragma unroll
      for (int j = 0; j < 8; ++j) acc = fmaf(x[j], W0i[r * 8 + j], acc);
#pragma unroll
      for (int j = 0; j < 4; ++j) acc = fmaf(h0[j], W0h[r * 4 + j], acc);
      g[r] = acc;
    }
    cell_update(g, h0, c0);
#pragma unroll
    for (int r = 0; r < 16; ++r) {
      float acc = b1[r];
#pragma unroll
      for (int j = 0; j < 4; ++j) acc = fmaf(h0[j], W1i[r * 4 + j], acc);
#pragma unroll
      for (int j = 0; j < 4; ++j) acc = fmaf(h1[j], W1h[r * 4 + j], acc);
      g[r] = acc;
    }
    cell_update(g, h1, c1);
  }

  // ---------------- decoder: 11 steps ----------------
  const float* dW0i = w + 352;
  const float* dW0h = w + 368;
  const float* db0 = w + 432;
  const float* dW1i = w + 448;
  const float* dW1h = w + 512;
  const float* db1 = w + 576;

  float xv = trg[(size_t)b * Tn];  // trg[b, 0, 0]
  out[(size_t)b * Tn] = xv;

  for (int t = 1; t < Tn; ++t) {
    float g[16];
#pragma unroll
    for (int r = 0; r < 16; ++r) {
      float acc = fmaf(xv, dW0i[r], db0[r]);
#pragma unroll
      for (int j = 0; j < 4; ++j) acc = fmaf(h0[j], dW0h[r * 4 + j], acc);
      g[r] = acc;
    }
    cell_update(g, h0, c0);
#pragma unroll
    for (int r = 0; r < 16; ++r) {
      float acc = db1[r];
#pragma unroll
      for (int j = 0; j < 4; ++j) acc = fmaf(h0[j], dW1i[r * 4 + j], acc);
#pragma unroll
      for (int j = 0; j < 4; ++j) acc = fmaf(h1[j], dW1h[r * 4 + j], acc);
      g[r] = acc;
    }
    cell_update(g, h1, c1);
    float pred = w[596];
#pragma unroll
    for (int j = 0; j < 4; ++j) pred = fmaf(h1[j], w[592 + j], pred);
    out[(size_t)b * Tn + t] = pred;
    xv = pred;
  }
}

}  // namespace

extern "C" void kernel_launch(void* const* d_in, const int* in_sizes, int n_in,
                              void* d_out, int out_size, void* d_ws, size_t ws_size,
                              hipStream_t stream) {
  const float* src = (const float*)d_in[0];
  const float* trg = (const float*)d_in[1];
  const float* eWih0 = (const float*)d_in[2];
  const float* eWhh0 = (const float*)d_in[3];
  const float* ebih0 = (const float*)d_in[4];
  const float* ebhh0 = (const float*)d_in[5];
  const float* eWih1 = (const float*)d_in[6];
  const float* eWhh1 = (const float*)d_in[7];
  const float* ebih1 = (const float*)d_in[8];
  const float* ebhh1 = (const float*)d_in[9];
  const float* dWih0 = (const float*)d_in[10];
  const float* dWhh0 = (const float*)d_in[11];
  const float* dbih0 = (const float*)d_in[12];
  const float* dbhh0 = (const float*)d_in[13];
  const float* dWih1 = (const float*)d_in[14];
  const float* dWhh1 = (const float*)d_in[15];
  const float* dbih1 = (const float*)d_in[16];
  const float* dbhh1 = (const float*)d_in[17];
  const float* fcW = (const float*)d_in[18];
  const float* fcb = (const float*)d_in[19];
  float* out = (float*)d_out;

  const int B = 32768;
  const int block = 64;
  const int grid = B / block;  // 512 blocks -> 2 waves/CU across all 256 CUs
  seq2seq_kernel<<<grid, block, 0, stream>>>(
      src, trg, eWih0, eWhh0, ebih0, ebhh0, eWih1, eWhh1, ebih1, ebhh1,
      dWih0, dWhh0, dbih0, dbhh0, dWih1, dWhh1, dbih1, dbhh1, fcW, fcb, out);
}

// Round 2
// 544.143 us; speedup vs baseline: 1.3382x; 1.3382x over previous
//
#include <hip/hip_runtime.h>

namespace {

constexpr int Sn = 256;   // encoder sequence length
constexpr int Tn = 12;    // decoder length

__device__ __forceinline__ float rcp_(float x) { return __builtin_amdgcn_rcpf(x); }
// sigmoid(x) = 1/(1+e^-x); saturates cleanly: e^inf -> inf -> rcp -> 0
__device__ __forceinline__ float sigm_(float x) { return rcp_(1.0f + __expf(-x)); }
// tanh(x) = 1 - 2/(e^{2x}+1); x->+inf: 1-0=1, x->-inf: 1-2=-1 (no inf/inf NaN)
__device__ __forceinline__ float tanh_(float x) { return 1.0f - 2.0f * rcp_(__expf(2.0f * x) + 1.0f); }

// quad_perm DPP: lane i reads lane sel_i of its 4-lane quad. VALU-rate cross-lane.
template <int CTRL>
__device__ __forceinline__ float qperm(float v) {
  return __int_as_float(
      __builtin_amdgcn_mov_dpp(__float_as_int(v), CTRL, 0xF, 0xF, true));
}
constexpr int DPP_XOR1 = 0xB1;  // [1,0,3,2]
constexpr int DPP_XOR2 = 0x4E;  // [2,3,0,1]
constexpr int DPP_XOR3 = 0x1B;  // [3,2,1,0]
constexpr int DPP_BC0 = 0x00;   // [0,0,0,0]

// One unit's (i,f,g,o) activations + state update. Returns new h for this unit.
__device__ __forceinline__ float unit_update(const float* g, float& c) {
  float iv = sigm_(g[0]);
  float fv = sigm_(g[1]);
  float gv = tanh_(g[2]);
  float ov = sigm_(g[3]);
  c = fmaf(fv, c, iv * gv);
  return ov * tanh_(c);
}

// Gather this quad's 4 h values into hg[k] = h[u^k] (permuted order; weights
// are loaded permuted to match).
__device__ __forceinline__ void quad_gather(float h, float* hg) {
  hg[0] = h;
  hg[1] = qperm<DPP_XOR1>(h);
  hg[2] = qperm<DPP_XOR2>(h);
  hg[3] = qperm<DPP_XOR3>(h);
}

__global__ __launch_bounds__(64) void seq2seq_kernel(
    const float* __restrict__ src, const float* __restrict__ trg,
    const float* __restrict__ eWih0, const float* __restrict__ eWhh0,
    const float* __restrict__ ebih0, const float* __restrict__ ebhh0,
    const float* __restrict__ eWih1, const float* __restrict__ eWhh1,
    const float* __restrict__ ebih1, const float* __restrict__ ebhh1,
    const float* __restrict__ dWih0, const float* __restrict__ dWhh0,
    const float* __restrict__ dbih0, const float* __restrict__ dbhh0,
    const float* __restrict__ dWih1, const float* __restrict__ dWhh1,
    const float* __restrict__ dbih1, const float* __restrict__ dbhh1,
    const float* __restrict__ fcW, const float* __restrict__ fcb,
    float* __restrict__ out) {
  const int gid = blockIdx.x * 64 + threadIdx.x;
  const int e = gid >> 2;  // batch element
  const int u = gid & 3;   // hidden unit owned by this lane

  // ---- per-lane encoder weights (registers), h-weights permuted by u^k ----
  float w0x[4][8], w0h[4][4], b0r[4];
  float w1i[4][4], w1h[4][4], b1r[4];
#pragma unroll
  for (int gi = 0; gi < 4; ++gi) {
    const int r = gi * 4 + u;  // rows u, 4+u, 8+u, 12+u
#pragma unroll
    for (int j = 0; j < 8; ++j) w0x[gi][j] = eWih0[r * 8 + j];
#pragma unroll
    for (int k = 0; k < 4; ++k) {
      w0h[gi][k] = eWhh0[r * 4 + (u ^ k)];
      w1i[gi][k] = eWih1[r * 4 + (u ^ k)];
      w1h[gi][k] = eWhh1[r * 4 + (u ^ k)];
    }
    b0r[gi] = ebih0[r] + ebhh0[r];
    b1r[gi] = ebih1[r] + ebhh1[r];
  }

  const float4* sp = (const float4*)(src + (size_t)e * (Sn * 8));

  float h0g[4] = {0, 0, 0, 0};  // h0g[k] = h0[u^k]
  float h1g[4] = {0, 0, 0, 0};
  float c0 = 0.0f, c1 = 0.0f;

  // ---------------- encoder: 256 steps ----------------
  for (int t = 0; t < Sn; ++t) {
    float4 xa = sp[2 * t];
    float4 xb = sp[2 * t + 1];
    float x[8] = {xa.x, xa.y, xa.z, xa.w, xb.x, xb.y, xb.z, xb.w};
    float g[4];
#pragma unroll
    for (int gi = 0; gi < 4; ++gi) {
      float acc = b0r[gi];
#pragma unroll
      for (int j = 0; j < 8; ++j) acc = fmaf(x[j], w0x[gi][j], acc);
#pragma unroll
      for (int k = 0; k < 4; ++k) acc = fmaf(h0g[k], w0h[gi][k], acc);
      g[gi] = acc;
    }
    float h0 = unit_update(g, c0);
    quad_gather(h0, h0g);
#pragma unroll
    for (int gi = 0; gi < 4; ++gi) {
      float acc = b1r[gi];
#pragma unroll
      for (int k = 0; k < 4; ++k) acc = fmaf(h0g[k], w1i[gi][k], acc);
#pragma unroll
      for (int k = 0; k < 4; ++k) acc = fmaf(h1g[k], w1h[gi][k], acc);
      g[gi] = acc;
    }
    float h1 = unit_update(g, c1);
    quad_gather(h1, h1g);
  }

  // ---- per-lane decoder weights (loaded after encoder to bound pressure) ----
  float dw0i[4], dw0h[4][4], db0[4];
  float dw1i[4][4], dw1h[4][4], db1[4];
  float fcw[4];
#pragma unroll
  for (int gi = 0; gi < 4; ++gi) {
    const int r = gi * 4 + u;
    dw0i[gi] = dWih0[r];  // shape (16,1)
#pragma unroll
    for (int k = 0; k < 4; ++k) {
      dw0h[gi][k] = dWhh0[r * 4 + (u ^ k)];
      dw1i[gi][k] = dWih1[r * 4 + (u ^ k)];
      dw1h[gi][k] = dWhh1[r * 4 + (u ^ k)];
    }
    db0[gi] = dbih0[r] + dbhh0[r];
    db1[gi] = dbih1[r] + dbhh1[r];
  }
#pragma unroll
  for (int k = 0; k < 4; ++k) fcw[k] = fcW[u ^ k];
  const float fcbv = fcb[0];

  // ---------------- decoder: 11 steps ----------------
  float xv = trg[(size_t)e * Tn];  // trg[e, 0, 0]
  if (u == 0) out[(size_t)e * Tn] = xv;

  for (int t = 1; t < Tn; ++t) {
    float g[4];
#pragma unroll
    for (int gi = 0; gi < 4; ++gi) {
      float acc = fmaf(xv, dw0i[gi], db0[gi]);
#pragma unroll
      for (int k = 0; k < 4; ++k) acc = fmaf(h0g[k], dw0h[gi][k], acc);
      g[gi] = acc;
    }
    float h0 = unit_update(g, c0);
    quad_gather(h0, h0g);
#pragma unroll
    for (int gi = 0; gi < 4; ++gi) {
      float acc = db1[gi];
#pragma unroll
      for (int k = 0; k < 4; ++k) acc = fmaf(h0g[k], dw1i[gi][k], acc);
#pragma unroll
      for (int k = 0; k < 4; ++k) acc = fmaf(h1g[k], dw1h[gi][k], acc);
      g[gi] = acc;
    }
    float h1 = unit_update(g, c1);
    quad_gather(h1, h1g);
    float pred = fcbv;
#pragma unroll
    for (int k = 0; k < 4; ++k) pred = fmaf(h1g[k], fcw[k], pred);
    // broadcast lane0's pred so all quad lanes stay bit-identical
    pred = qperm<DPP_BC0>(pred);
    if (u == 0) out[(size_t)e * Tn + t] = pred;
    xv = pred;
  }
}

}  // namespace

extern "C" void kernel_launch(void* const* d_in, const int* in_sizes, int n_in,
                              void* d_out, int out_size, void* d_ws, size_t ws_size,
                              hipStream_t stream) {
  const float* src = (const float*)d_in[0];
  const float* trg = (const float*)d_in[1];
  const float* eWih0 = (const float*)d_in[2];
  const float* eWhh0 = (const float*)d_in[3];
  const float* ebih0 = (const float*)d_in[4];
  const float* ebhh0 = (const float*)d_in[5];
  const float* eWih1 = (const float*)d_in[6];
  const float* eWhh1 = (const float*)d_in[7];
  const float* ebih1 = (const float*)d_in[8];
  const float* ebhh1 = (const float*)d_in[9];
  const float* dWih0 = (const float*)d_in[10];
  const float* dWhh0 = (const float*)d_in[11];
  const float* dbih0 = (const float*)d_in[12];
  const float* dbhh0 = (const float*)d_in[13];
  const float* dWih1 = (const float*)d_in[14];
  const float* dWhh1 = (const float*)d_in[15];
  const float* dbih1 = (const float*)d_in[16];
  const float* dbhh1 = (const float*)d_in[17];
  const float* fcW = (const float*)d_in[18];
  const float* fcb = (const float*)d_in[19];
  float* out = (float*)d_out;

  const int B = 32768;
  const int lanes = B * 4;          // 4 lanes per batch element
  const int block = 64;
  const int grid = lanes / block;   // 2048 blocks -> 8 waves/CU, 2/SIMD
  seq2seq_kernel<<<grid, block, 0, stream>>>(
      src, trg, eWih0, eWhh0, ebih0, ebhh0, eWih1, eWhh1, ebih1, ebhh1,
      dWih0, dWhh0, dbih0, dbhh0, dWih1, dWhh1, dbih1, dbhh1, fcW, fcb, out);
}

// Round 3
// 475.889 us; speedup vs baseline: 1.5301x; 1.1434x over previous
//
#include <hip/hip_runtime.h>

namespace {

constexpr int Sn = 256;   // encoder sequence length
constexpr int Tn = 12;    // decoder length

typedef float v2f __attribute__((ext_vector_type(2)));

__device__ __forceinline__ v2f pkfma(v2f a, v2f b, v2f c) {
  return __builtin_elementwise_fma(a, b, c);  // -> v_pk_fma_f32 on gfx950
}

__device__ __forceinline__ float rcp_(float x) { return __builtin_amdgcn_rcpf(x); }
// sigmoid(x) = 1/(1+e^-x); saturates cleanly: e^inf -> inf -> rcp -> 0
__device__ __forceinline__ float sigm_(float x) { return rcp_(1.0f + __expf(-x)); }
// tanh(x) = 1 - 2/(e^{2x}+1); x->+inf: 1-0=1, x->-inf: 1-2=-1 (no inf/inf NaN)
__device__ __forceinline__ float tanh_(float x) { return 1.0f - 2.0f * rcp_(__expf(2.0f * x) + 1.0f); }

// quad_perm DPP: lane i reads lane sel_i of its 4-lane quad. VALU-rate cross-lane.
template <int CTRL>
__device__ __forceinline__ float qperm(float v) {
  return __int_as_float(
      __builtin_amdgcn_mov_dpp(__float_as_int(v), CTRL, 0xF, 0xF, true));
}
constexpr int DPP_XOR1 = 0xB1;  // [1,0,3,2]
constexpr int DPP_XOR2 = 0x4E;  // [2,3,0,1]
constexpr int DPP_XOR3 = 0x1B;  // [3,2,1,0]
constexpr int DPP_BC0 = 0x00;   // [0,0,0,0]

// g01=(i,f), g23=(g,o) pre-activation; updates c, returns new h.
__device__ __forceinline__ float unit_update(v2f g01, v2f g23, float& c) {
  float iv = sigm_(g01.x);
  float fv = sigm_(g01.y);
  float gv = tanh_(g23.x);
  float ov = sigm_(g23.y);
  c = fmaf(fv, c, iv * gv);
  return ov * tanh_(c);
}

__device__ __forceinline__ void quad_gather(float h, float* hg) {
  hg[0] = h;
  hg[1] = qperm<DPP_XOR1>(h);
  hg[2] = qperm<DPP_XOR2>(h);
  hg[3] = qperm<DPP_XOR3>(h);
}

__global__ __launch_bounds__(64) void seq2seq_kernel(
    const float* __restrict__ src, const float* __restrict__ trg,
    const float* __restrict__ eWih0, const float* __restrict__ eWhh0,
    const float* __restrict__ ebih0, const float* __restrict__ ebhh0,
    const float* __restrict__ eWih1, const float* __restrict__ eWhh1,
    const float* __restrict__ ebih1, const float* __restrict__ ebhh1,
    const float* __restrict__ dWih0, const float* __restrict__ dWhh0,
    const float* __restrict__ dbih0, const float* __restrict__ dbhh0,
    const float* __restrict__ dWih1, const float* __restrict__ dWhh1,
    const float* __restrict__ dbih1, const float* __restrict__ dbhh1,
    const float* __restrict__ fcW, const float* __restrict__ fcb,
    float* __restrict__ out) {
  const int gid = blockIdx.x * 64 + threadIdx.x;
  const int e = gid >> 2;  // batch element
  const int u = gid & 3;   // hidden unit owned by this lane

  // Gate rows for this lane: i=u, f=4+u, g=8+u, o=12+u.
  // Packed pairs: 01=(i,f), 23=(g,o). h-indices permuted by u^k to match the
  // quad_gather register order.
  const int ri = u, rf = 4 + u, rg = 8 + u, ro = 12 + u;

  v2f w0x01[8], w0x23[8], w0h01[4], w0h23[4];
  v2f w1i01[4], w1i23[4], w1h01[4], w1h23[4];
#pragma unroll
  for (int j = 0; j < 8; ++j) {
    w0x01[j] = v2f{eWih0[ri * 8 + j], eWih0[rf * 8 + j]};
    w0x23[j] = v2f{eWih0[rg * 8 + j], eWih0[ro * 8 + j]};
  }
#pragma unroll
  for (int k = 0; k < 4; ++k) {
    const int kc = u ^ k;
    w0h01[k] = v2f{eWhh0[ri * 4 + kc], eWhh0[rf * 4 + kc]};
    w0h23[k] = v2f{eWhh0[rg * 4 + kc], eWhh0[ro * 4 + kc]};
    w1i01[k] = v2f{eWih1[ri * 4 + kc], eWih1[rf * 4 + kc]};
    w1i23[k] = v2f{eWih1[rg * 4 + kc], eWih1[ro * 4 + kc]};
    w1h01[k] = v2f{eWhh1[ri * 4 + kc], eWhh1[rf * 4 + kc]};
    w1h23[k] = v2f{eWhh1[rg * 4 + kc], eWhh1[ro * 4 + kc]};
  }
  const v2f b0_01 = v2f{ebih0[ri] + ebhh0[ri], ebih0[rf] + ebhh0[rf]};
  const v2f b0_23 = v2f{ebih0[rg] + ebhh0[rg], ebih0[ro] + ebhh0[ro]};
  const v2f b1_01 = v2f{ebih1[ri] + ebhh1[ri], ebih1[rf] + ebhh1[rf]};
  const v2f b1_23 = v2f{ebih1[rg] + ebhh1[rg], ebih1[ro] + ebhh1[ro]};

  const float4* sp = (const float4*)(src + (size_t)e * (Sn * 8));

  float h0g[4] = {0, 0, 0, 0};  // h0g[k] = h0[u^k]
  float h1g[4] = {0, 0, 0, 0};
  float c0 = 0.0f, c1 = 0.0f;

  // ---------------- encoder: 256 steps, x prefetched one step ahead --------
  float4 xa = sp[0], xb = sp[1];
  for (int t = 0; t < Sn; ++t) {
    // issue next step's loads before the ~400-cycle compute body
    const int tn = (t < Sn - 1) ? t + 1 : t;
    float4 na = sp[2 * tn];
    float4 nb = sp[2 * tn + 1];

    float x[8] = {xa.x, xa.y, xa.z, xa.w, xb.x, xb.y, xb.z, xb.w};
    v2f a01 = b0_01, a23 = b0_23;
#pragma unroll
    for (int j = 0; j < 8; ++j) {
      v2f xx = v2f{x[j], x[j]};
      a01 = pkfma(xx, w0x01[j], a01);
      a23 = pkfma(xx, w0x23[j], a23);
    }
#pragma unroll
    for (int k = 0; k < 4; ++k) {
      v2f hh = v2f{h0g[k], h0g[k]};
      a01 = pkfma(hh, w0h01[k], a01);
      a23 = pkfma(hh, w0h23[k], a23);
    }
    float h0 = unit_update(a01, a23, c0);
    quad_gather(h0, h0g);

    a01 = b1_01;
    a23 = b1_23;
#pragma unroll
    for (int k = 0; k < 4; ++k) {
      v2f hh0 = v2f{h0g[k], h0g[k]};
      v2f hh1 = v2f{h1g[k], h1g[k]};
      a01 = pkfma(hh0, w1i01[k], a01);
      a23 = pkfma(hh0, w1i23[k], a23);
      a01 = pkfma(hh1, w1h01[k], a01);
      a23 = pkfma(hh1, w1h23[k], a23);
    }
    float h1 = unit_update(a01, a23, c1);
    quad_gather(h1, h1g);

    xa = na;
    xb = nb;
  }

  // ---- decoder weights (loaded after encoder; encoder weights now dead) ----
  v2f dw0i01 = v2f{dWih0[ri], dWih0[rf]};
  v2f dw0i23 = v2f{dWih0[rg], dWih0[ro]};
  v2f dw0h01[4], dw0h23[4], dw1i01[4], dw1i23[4], dw1h01[4], dw1h23[4];
#pragma unroll
  for (int k = 0; k < 4; ++k) {
    const int kc = u ^ k;
    dw0h01[k] = v2f{dWhh0[ri * 4 + kc], dWhh0[rf * 4 + kc]};
    dw0h23[k] = v2f{dWhh0[rg * 4 + kc], dWhh0[ro * 4 + kc]};
    dw1i01[k] = v2f{dWih1[ri * 4 + kc], dWih1[rf * 4 + kc]};
    dw1i23[k] = v2f{dWih1[rg * 4 + kc], dWih1[ro * 4 + kc]};
    dw1h01[k] = v2f{dWhh1[ri * 4 + kc], dWhh1[rf * 4 + kc]};
    dw1h23[k] = v2f{dWhh1[rg * 4 + kc], dWhh1[ro * 4 + kc]};
  }
  const v2f db0_01 = v2f{dbih0[ri] + dbhh0[ri], dbih0[rf] + dbhh0[rf]};
  const v2f db0_23 = v2f{dbih0[rg] + dbhh0[rg], dbih0[ro] + dbhh0[ro]};
  const v2f db1_01 = v2f{dbih1[ri] + dbhh1[ri], dbih1[rf] + dbhh1[rf]};
  const v2f db1_23 = v2f{dbih1[rg] + dbhh1[rg], dbih1[ro] + dbhh1[ro]};
  float fcw[4];
#pragma unroll
  for (int k = 0; k < 4; ++k) fcw[k] = fcW[u ^ k];
  const float fcbv = fcb[0];

  // ---------------- decoder: 11 steps ----------------
  float xv = trg[(size_t)e * Tn];  // trg[e, 0, 0]
  if (u == 0) out[(size_t)e * Tn] = xv;

  for (int t = 1; t < Tn; ++t) {
    v2f xx = v2f{xv, xv};
    v2f a01 = pkfma(xx, dw0i01, db0_01);
    v2f a23 = pkfma(xx, dw0i23, db0_23);
#pragma unroll
    for (int k = 0; k < 4; ++k) {
      v2f hh = v2f{h0g[k], h0g[k]};
      a01 = pkfma(hh, dw0h01[k], a01);
      a23 = pkfma(hh, dw0h23[k], a23);
    }
    float h0 = unit_update(a01, a23, c0);
    quad_gather(h0, h0g);

    a01 = db1_01;
    a23 = db1_23;
#pragma unroll
    for (int k = 0; k < 4; ++k) {
      v2f hh0 = v2f{h0g[k], h0g[k]};
      v2f hh1 = v2f{h1g[k], h1g[k]};
      a01 = pkfma(hh0, dw1i01[k], a01);
      a23 = pkfma(hh0, dw1i23[k], a23);
      a01 = pkfma(hh1, dw1h01[k], a01);
      a23 = pkfma(hh1, dw1h23[k], a23);
    }
    float h1 = unit_update(a01, a23, c1);
    quad_gather(h1, h1g);

    float pred = fcbv;
#pragma unroll
    for (int k = 0; k < 4; ++k) pred = fmaf(h1g[k], fcw[k], pred);
    // broadcast lane0's pred so all quad lanes stay bit-identical
    pred = qperm<DPP_BC0>(pred);
    if (u == 0) out[(size_t)e * Tn + t] = pred;
    xv = pred;
  }
}

}  // namespace

extern "C" void kernel_launch(void* const* d_in, const int* in_sizes, int n_in,
                              void* d_out, int out_size, void* d_ws, size_t ws_size,
                              hipStream_t stream) {
  const float* src = (const float*)d_in[0];
  const float* trg = (const float*)d_in[1];
  const float* eWih0 = (const float*)d_in[2];
  const float* eWhh0 = (const float*)d_in[3];
  const float* ebih0 = (const float*)d_in[4];
  const float* ebhh0 = (const float*)d_in[5];
  const float* eWih1 = (const float*)d_in[6];
  const float* eWhh1 = (const float*)d_in[7];
  const float* ebih1 = (const float*)d_in[8];
  const float* ebhh1 = (const float*)d_in[9];
  const float* dWih0 = (const float*)d_in[10];
  const float* dWhh0 = (const float*)d_in[11];
  const float* dbih0 = (const float*)d_in[12];
  const float* dbhh0 = (const float*)d_in[13];
  const float* dWih1 = (const float*)d_in[14];
  const float* dWhh1 = (const float*)d_in[15];
  const float* dbih1 = (const float*)d_in[16];
  const float* dbhh1 = (const float*)d_in[17];
  const float* fcW = (const float*)d_in[18];
  const float* fcb = (const float*)d_in[19];
  float* out = (float*)d_out;

  const int B = 32768;
  const int lanes = B * 4;          // 4 lanes per batch element
  const int block = 64;
  const int grid = lanes / block;   // 2048 blocks -> 8 waves/CU, 2/SIMD
  seq2seq_kernel<<<grid, block, 0, stream>>>(
      src, trg, eWih0, eWhh0, ebih0, ebhh0, eWih1, eWhh1, ebih1, ebhh1,
      dWih0, dWhh0, dbih0, dbhh0, dWih1, dWhh1, dbih1, dbhh1, fcW, fcb, out);
}